// Round 9
// baseline (173.953 us; speedup 1.0000x reference)
//
#include <hip/hip_runtime.h>

#define NN 100
#define EE 262144
#define NSC 64          // scatter blocks / partial histograms
#define NB2 128         // mega-kernel blocks
#define NT2 256

// ws float offsets:
//   P    @ 0      : 64*10000 = 640000
//   D    @ 640000 : 64*100   = 6400
//   MS   @ 646400 : 512        (BN sum/sumsq; zeroed by scatter blk 0)
//   bar  @ 646912 : 16 ints    (grid barrier counters; zeroed by scatter blk 0)
//   Ssum @ 646928 : 10000
//   deg  @ 656928 : 100
//   h2   @ 657028 : 12800
//   h3   @ 669828 : 25600
#define WS_D    640000
#define WS_MS   646400
#define WS_BAR  646912
#define WS_SS   646928
#define WS_DEG  656928
#define WS_H2   657028
#define WS_H3   669828

// ---- K1: scatter, 64 blocks x 512 thr (R6-proven) + degree partials ----
__global__ __launch_bounds__(512) void scatter_kernel(
    const int* __restrict__ ei, const float* __restrict__ ew,
    float* __restrict__ P, float* __restrict__ D,
    float* __restrict__ MS, int* __restrict__ bar)
{
    __shared__ float hist[NN * NN];          // 40 KB
    __shared__ float part[NN][4];
    const int tid = threadIdx.x, blk = blockIdx.x;
    for (int i = tid; i < 2500; i += 512)
        ((float4*)hist)[i] = make_float4(0.f, 0.f, 0.f, 0.f);
    if (blk == 0) {
        if (tid < 128) ((float4*)MS)[tid] = make_float4(0.f, 0.f, 0.f, 0.f);
        if (tid >= 128 && tid < 144) bar[tid - 128] = 0;
    }
    __syncthreads();
    const int base = blk * 1024;             // 1024 quads = 4096 edges / block
#pragma unroll
    for (int q = base + tid; q < base + 1024; q += 512) {
        int4   s4 = ((const int4*)ei)[q];
        int4   d4 = ((const int4*)(ei + EE))[q];
        float4 w4 = ((const float4*)ew)[q];
        atomicAdd(&hist[d4.x * NN + s4.x], w4.x);    // ds_add_f32
        atomicAdd(&hist[d4.y * NN + s4.y], w4.y);
        atomicAdd(&hist[d4.z * NN + s4.z], w4.z);
        atomicAdd(&hist[d4.w * NN + s4.w], w4.w);
    }
    __syncthreads();
    for (int i = tid; i < 2500; i += 512)
        ((float4*)(P + blk * 10000))[i] = ((const float4*)hist)[i];
    if (tid < 400) {                         // row-degree partials
        int row = tid >> 2, q = tid & 3;
        const float* r = hist + row * NN + q * 25;
        float s = 0.f;
#pragma unroll
        for (int k = 0; k < 25; ++k) s += r[k];
        part[row][q] = s;
    }
    __syncthreads();
    if (tid < NN)
        D[blk * NN + tid] = part[tid][0] + part[tid][1] + part[tid][2] + part[tid][3];
}

// Device-scope grid barrier (R5-proven). All NB2 blocks resident.
__device__ __forceinline__ void gridbar(int* bar, int k) {
    __threadfence();                      // release (wbL2 → cross-XCD visible)
    __syncthreads();
    if (threadIdx.x == 0) {
        atomicAdd(&bar[k], 1);
        for (int it = 0; it < (1 << 22); ++it) {   // capped spin (hang guard)
            if (__hip_atomic_load(&bar[k], __ATOMIC_RELAXED,
                                  __HIP_MEMORY_SCOPE_AGENT) >= NB2) break;
            __builtin_amdgcn_s_sleep(1);
        }
        __threadfence();                  // acquire (invalidate L1/L2)
    }
    __syncthreads();
}

// ---- K2: mega (128 blocks x 256 thr, 3 grid barriers) ----
__global__ __launch_bounds__(NT2) void mega_kernel(
    const float* __restrict__ x,
    const float* __restrict__ W1, const float* __restrict__ b1,
    const float* __restrict__ W2, const float* __restrict__ b2,
    const float* __restrict__ W3, const float* __restrict__ b3,
    const float* __restrict__ gamma, const float* __restrict__ beta,
    const float* __restrict__ lw1, const float* __restrict__ lb1,
    const float* __restrict__ lw2, const float* __restrict__ lb2,
    float* __restrict__ ws, float* __restrict__ out)
{
    __shared__ float lds[24000];             // 96 KB, phase-overlaid
    float* P    = ws;
    float* D    = ws + WS_D;
    float* MS   = ws + WS_MS;
    int*   bar  = (int*)(ws + WS_BAR);
    float* Ssum = ws + WS_SS;
    float* degg = ws + WS_DEG;
    float* h2g  = ws + WS_H2;
    float* h3g  = ws + WS_H3;
    const int tid = threadIdx.x, blk = blockIdx.x;

    // ---- phase A: reduce P -> Ssum row + degree (blocks 0..99) ----
    if (blk < NN) {
        float* row = lds + 10000;
        if (tid < NN) {
            float s = 0.f;
#pragma unroll 8
            for (int p = 0; p < NSC; ++p) s += P[p * 10000 + blk * NN + tid];
            row[tid] = s;
            Ssum[blk * NN + tid] = s;
        }
        float dsum = 0.f;
        if (tid < NN) {
            float dd = 0.f;
#pragma unroll
            for (int p = 0; p < NSC; ++p) dd += D[p * NN + tid];
            dsum = dd;                       // (parallel D-sum, reused below)
        }
        __syncthreads();
        if (tid == 0) {
            float deg = 1.f;
            for (int i = 0; i < NN; ++i) deg += row[i];
            degg[blk] = deg;
        }
        (void)dsum;
    }
    gridbar(bar, 0);

    // ---- phase B: dinv + full A (LDS-resident) + full L1 + own h2 row ----
    float* A = lds;                          // 10000, persists through phase C
    if (blk < NN) {
        float* xl  = lds + 10000;            // 2800
        float* g1  = lds + 12800;            // 2800
        float* W1l = lds + 15600;            // 1728
        float* b1l = lds + 17328;            // 64
        float* dv  = lds + 17392;            // 100
        float* h1l = lds + 17492;            // 6400
        float* g2  = lds + 23892;            // 64
        const int d = blk;

        for (int i = tid; i < NN * 28; i += NT2) {
            int n = i / 28, c = i - n * 28;
            xl[i] = (c < 27) ? x[n * 27 + c] : 0.f;
        }
        for (int i = tid; i < 27 * 64; i += NT2) W1l[i] = W1[i];
        if (tid < 64) b1l[tid] = b1[tid];
        if (tid < NN) dv[tid] = rsqrtf(degg[tid]);
        __syncthreads();

        // A = dinv ⊗ dinv · Ssum (+ dinv² diag)
        for (int i4 = tid; i4 < 2500; i4 += NT2) {
            float4 s = ((const float4*)Ssum)[i4];
            int r = i4 / 25, c0 = (i4 - r * 25) * 4;
            float dr = dv[r], dd2 = dr * dr;
            float4 a;
            a.x = dr * dv[c0 + 0] * s.x; if (r == c0 + 0) a.x += dd2;
            a.y = dr * dv[c0 + 1] * s.y; if (r == c0 + 1) a.y += dd2;
            a.z = dr * dv[c0 + 2] * s.z; if (r == c0 + 2) a.z += dd2;
            a.w = dr * dv[c0 + 3] * s.w; if (r == c0 + 3) a.w += dd2;
            ((float4*)A)[i4] = a;
        }
        __syncthreads();

        // g1 = A @ x (175 tile-jobs < 256 threads)
        if (tid < 175) {
            int nt = tid / 7, n0 = nt * 4, c0 = (tid - nt * 7) * 4;
            float acc[4][4];
#pragma unroll
            for (int r = 0; r < 4; ++r)
#pragma unroll
                for (int q = 0; q < 4; ++q) acc[r][q] = 0.f;
            for (int m = 0; m < NN; m += 4) {
                float4 a0 = *(const float4*)(A + (n0 + 0) * NN + m);
                float4 a1 = *(const float4*)(A + (n0 + 1) * NN + m);
                float4 a2 = *(const float4*)(A + (n0 + 2) * NN + m);
                float4 a3 = *(const float4*)(A + (n0 + 3) * NN + m);
                float4 x0 = *(const float4*)(xl + (m + 0) * 28 + c0);
                float4 x1 = *(const float4*)(xl + (m + 1) * 28 + c0);
                float4 x2 = *(const float4*)(xl + (m + 2) * 28 + c0);
                float4 x3 = *(const float4*)(xl + (m + 3) * 28 + c0);
#define GROW(r, ar) \
                acc[r][0] += ar.x*x0.x + ar.y*x1.x + ar.z*x2.x + ar.w*x3.x; \
                acc[r][1] += ar.x*x0.y + ar.y*x1.y + ar.z*x2.y + ar.w*x3.y; \
                acc[r][2] += ar.x*x0.z + ar.y*x1.z + ar.z*x2.z + ar.w*x3.z; \
                acc[r][3] += ar.x*x0.w + ar.y*x1.w + ar.z*x2.w + ar.w*x3.w;
                GROW(0, a0) GROW(1, a1) GROW(2, a2) GROW(3, a3)
#undef GROW
            }
#pragma unroll
            for (int r = 0; r < 4; ++r)
                *(float4*)(g1 + (n0 + r) * 28 + c0) =
                    make_float4(acc[r][0], acc[r][1], acc[r][2], acc[r][3]);
        }
        __syncthreads();

        // h1 = relu(g1 @ W1 + b1): 400 tile-jobs, grid-stride over 256 thr
        for (int t = tid; t < 400; t += NT2) {
            int nt = t / 16, n0 = nt * 4, j0 = (t - nt * 16) * 4;
            float acc[4][4];
#pragma unroll
            for (int r = 0; r < 4; ++r)
#pragma unroll
                for (int q = 0; q < 4; ++q) acc[r][q] = 0.f;
            for (int c = 0; c < 24; c += 4) {
                float4 w0 = *(const float4*)(W1l + (c + 0) * 64 + j0);
                float4 w1 = *(const float4*)(W1l + (c + 1) * 64 + j0);
                float4 w2 = *(const float4*)(W1l + (c + 2) * 64 + j0);
                float4 w3 = *(const float4*)(W1l + (c + 3) * 64 + j0);
                float4 g0 = *(const float4*)(g1 + (n0 + 0) * 28 + c);
                float4 g1_ = *(const float4*)(g1 + (n0 + 1) * 28 + c);
                float4 g2_ = *(const float4*)(g1 + (n0 + 2) * 28 + c);
                float4 g3_ = *(const float4*)(g1 + (n0 + 3) * 28 + c);
#define TROW(r, gr) \
                acc[r][0] += gr.x*w0.x + gr.y*w1.x + gr.z*w2.x + gr.w*w3.x; \
                acc[r][1] += gr.x*w0.y + gr.y*w1.y + gr.z*w2.y + gr.w*w3.y; \
                acc[r][2] += gr.x*w0.z + gr.y*w1.z + gr.z*w2.z + gr.w*w3.z; \
                acc[r][3] += gr.x*w0.w + gr.y*w1.w + gr.z*w2.w + gr.w*w3.w;
                TROW(0, g0) TROW(1, g1_) TROW(2, g2_) TROW(3, g3_)
#undef TROW
            }
#pragma unroll
            for (int c = 24; c < 27; ++c) {
                float4 wq = *(const float4*)(W1l + c * 64 + j0);
#pragma unroll
                for (int r = 0; r < 4; ++r) {
                    float gv = g1[(n0 + r) * 28 + c];
                    acc[r][0] += gv * wq.x; acc[r][1] += gv * wq.y;
                    acc[r][2] += gv * wq.z; acc[r][3] += gv * wq.w;
                }
            }
            float4 bq = *(const float4*)(b1l + j0);
#pragma unroll
            for (int r = 0; r < 4; ++r) {
                float4 v;
                v.x = fmaxf(acc[r][0] + bq.x, 0.f); v.y = fmaxf(acc[r][1] + bq.y, 0.f);
                v.z = fmaxf(acc[r][2] + bq.z, 0.f); v.w = fmaxf(acc[r][3] + bq.w, 0.f);
                *(float4*)(h1l + (n0 + r) * 64 + j0) = v;
            }
        }
        __syncthreads();

        // g2 = A[d] @ h1 (own row)
        if (tid < 64) {
            const float* Ar = A + d * NN;
            float acc = 0.f;
#pragma unroll 4
            for (int m = 0; m < NN; ++m) acc += Ar[m] * h1l[m * 64 + tid];
            g2[tid] = acc;
        }
        __syncthreads();

        // h2 row = relu(g2 @ W2 + b2)
        if (tid < 128) {
            float acc = b2[tid];
#pragma unroll 8
            for (int c = 0; c < 64; ++c) acc += g2[c] * W2[c * 128 + tid];
            h2g[d * 128 + tid] = fmaxf(acc, 0.f);
        }
    }
    gridbar(bar, 1);

    // ---- phase C: own g3/h3 row + BN stats (A still LDS-resident) ----
    if (blk < NN) {
        float* h2l = lds + 10000;            // 12800
        float* g3  = lds + 22800;            // 128
        const int d = blk;
        for (int i = tid; i < NN * 32; i += NT2)
            ((float4*)h2l)[i] = ((const float4*)h2g)[i];
        __syncthreads();
        if (tid < 128) {
            const float* Ar = A + d * NN;
            float acc = 0.f;
#pragma unroll 4
            for (int m = 0; m < NN; ++m) acc += Ar[m] * h2l[m * 128 + tid];
            g3[tid] = acc;
        }
        __syncthreads();
        {
            int j = tid;
            float acc = b3[j];
#pragma unroll 8
            for (int c = 0; c < 128; ++c) acc += g3[c] * W3[c * 256 + j];
            float v = fmaxf(acc, 0.f);
            h3g[d * 256 + j] = v;
            atomicAdd(&MS[j], v);
            atomicAdd(&MS[256 + j], v * v);
        }
    }
    gridbar(bar, 2);

    // ---- phase D: BN fold + redundant y + own out[j] (all 128 blocks) ----
    {
        float* sc   = lds;                   // 256
        float* sh   = lds + 256;             // 256
        float* wsc  = lds + 512;             // 2560
        float* cst  = lds + 3072;            // 10
        float* yl   = lds + 3082;            // 1000
        float* partw= lds + 4082;            // 4
        const int j = blk;

        {
            float s1 = MS[tid], s2 = MS[256 + tid];
            float mu  = s1 * 0.01f;
            float var = s2 * 0.01f - mu * mu;
            float s   = gamma[tid] * rsqrtf(var + 1e-5f);
            sc[tid] = s;
            sh[tid] = beta[tid] - mu * s;
        }
        __syncthreads();
        for (int i = tid; i < 2560; i += NT2) wsc[i] = sc[i & 255] * lw1[i];
        if (tid < 10) {
            float a = lb1[tid];
            const float* w = lw1 + tid * 256;
#pragma unroll 4
            for (int c = 0; c < 256; ++c) a += sh[c] * w[c];
            cst[tid] = a;
        }
        __syncthreads();

        if (tid < 250) {                     // y redundant: 2n x 2k reg tiles
            int n0 = (tid / 5) * 2, k0 = (tid % 5) * 2;
            float a00 = 0.f, a01 = 0.f, a10 = 0.f, a11 = 0.f;
            for (int c = 0; c < 256; c += 4) {
                float4 hA = *(const float4*)(h3g + n0 * 256 + c);
                float4 hB = *(const float4*)(h3g + (n0 + 1) * 256 + c);
                float4 wA = *(const float4*)(wsc + k0 * 256 + c);
                float4 wB = *(const float4*)(wsc + (k0 + 1) * 256 + c);
                a00 += hA.x*wA.x + hA.y*wA.y + hA.z*wA.z + hA.w*wA.w;
                a01 += hA.x*wB.x + hA.y*wB.y + hA.z*wB.z + hA.w*wB.w;
                a10 += hB.x*wA.x + hB.y*wA.y + hB.z*wA.z + hB.w*wA.w;
                a11 += hB.x*wB.x + hB.y*wB.y + hB.z*wB.z + hB.w*wB.w;
            }
            yl[n0 * 10 + k0]           = fmaxf(a00 + cst[k0], 0.f);
            yl[n0 * 10 + k0 + 1]       = fmaxf(a01 + cst[k0 + 1], 0.f);
            yl[(n0 + 1) * 10 + k0]     = fmaxf(a10 + cst[k0], 0.f);
            yl[(n0 + 1) * 10 + k0 + 1] = fmaxf(a11 + cst[k0 + 1], 0.f);
        }
        __syncthreads();

        float acc = 0.f;
        if (tid < 250) {
            float4 a = ((const float4*)yl)[tid];
            float4 b = ((const float4*)(lw2 + j * 1000))[tid];
            acc = a.x * b.x + a.y * b.y + a.z * b.z + a.w * b.w;
        }
#pragma unroll
        for (int off = 32; off; off >>= 1) acc += __shfl_down(acc, off);
        if ((tid & 63) == 0) partw[tid >> 6] = acc;
        __syncthreads();
        if (tid == 0)
            out[j] = partw[0] + partw[1] + partw[2] + partw[3] + lb2[j];
    }
}

extern "C" void kernel_launch(void* const* d_in, const int* in_sizes, int n_in,
                              void* d_out, int out_size, void* d_ws, size_t ws_size,
                              hipStream_t stream) {
    const float* x     = (const float*)d_in[0];
    const int*   ei    = (const int*)d_in[1];
    const float* ew    = (const float*)d_in[2];
    const float* W1    = (const float*)d_in[3];
    const float* b1    = (const float*)d_in[4];
    const float* W2    = (const float*)d_in[5];
    const float* b2    = (const float*)d_in[6];
    const float* W3    = (const float*)d_in[7];
    const float* b3    = (const float*)d_in[8];
    const float* gamma = (const float*)d_in[9];
    const float* beta  = (const float*)d_in[10];
    const float* lw1   = (const float*)d_in[11];
    const float* lb1   = (const float*)d_in[12];
    const float* lw2   = (const float*)d_in[13];
    const float* lb2   = (const float*)d_in[14];

    float* ws  = (float*)d_ws;
    float* out = (float*)d_out;

    scatter_kernel<<<NSC, 512, 0, stream>>>(ei, ew, ws, ws + WS_D,
                                            ws + WS_MS, (int*)(ws + WS_BAR));
    mega_kernel<<<NB2, NT2, 0, stream>>>(x, W1, b1, W2, b2, W3, b3,
                                         gamma, beta, lw1, lb1, lw2, lb2,
                                         ws, out);
}

// Round 10
// 138.675 us; speedup vs baseline: 1.2544x; 1.2544x over previous
//
#include <hip/hip_runtime.h>

#define NN 100
#define EE 262144
#define NP 64

// ws float offsets:
//   P  @ 0      : 64*10000 = 640000   (scatter partial histograms)
//   D  @ 640000 : 64*100   = 6400     (scatter partial row degrees)
//   MS @ 646400 : 512                 (BN sum/sumsq; zeroed by scatter blk 0)
//   A  @ 646912 : 10000
//   h1 @ 656912 : 6400
//   h2 @ 663312 : 12800
//   h3 @ 676112 : 25600
#define WS_D   640000
#define WS_MS  646400
#define WS_A   646912
#define WS_H1  656912
#define WS_H2  663312
#define WS_H3  676112

// ---- 1. scatter: per-block LDS histogram + degree partials (R6-proven) ----
__global__ __launch_bounds__(512) void scatter_kernel(
    const int* __restrict__ ei, const float* __restrict__ ew,
    float* __restrict__ P, float* __restrict__ D, float* __restrict__ MS)
{
    __shared__ float hist[NN * NN];          // 40 KB
    __shared__ float part[NN][4];
    const int tid = threadIdx.x, blk = blockIdx.x;
    for (int i = tid; i < 2500; i += 512)
        ((float4*)hist)[i] = make_float4(0.f, 0.f, 0.f, 0.f);
    if (blk == 0 && tid < 128)
        ((float4*)MS)[tid] = make_float4(0.f, 0.f, 0.f, 0.f);
    __syncthreads();
    const int base = blk * 1024;             // 1024 quads = 4096 edges / block
#pragma unroll
    for (int q = base + tid; q < base + 1024; q += 512) {
        int4   s4 = ((const int4*)ei)[q];
        int4   d4 = ((const int4*)(ei + EE))[q];
        float4 w4 = ((const float4*)ew)[q];
        atomicAdd(&hist[d4.x * NN + s4.x], w4.x);    // ds_add_f32
        atomicAdd(&hist[d4.y * NN + s4.y], w4.y);
        atomicAdd(&hist[d4.z * NN + s4.z], w4.z);
        atomicAdd(&hist[d4.w * NN + s4.w], w4.w);
    }
    __syncthreads();
    for (int i = tid; i < 2500; i += 512)
        ((float4*)(P + blk * 10000))[i] = ((const float4*)hist)[i];
    if (tid < 400) {                         // row-degree partials
        int row = tid >> 2, q = tid & 3;
        const float* r = hist + row * NN + q * 25;
        float s = 0.f;
#pragma unroll
        for (int k = 0; k < 25; ++k) s += r[k];
        part[row][q] = s;
    }
    __syncthreads();
    if (tid < NN)
        D[blk * NN + tid] = part[tid][0] + part[tid][1] + part[tid][2] + part[tid][3];
}

// ---- 2. a_l1: dinv + own A row (from P directly) + own h1 row ----
__global__ __launch_bounds__(256) void a_l1_kernel(
    const float* __restrict__ P, const float* __restrict__ D,
    const float* __restrict__ x, const float* __restrict__ W1,
    const float* __restrict__ b1, float* __restrict__ Ag,
    float* __restrict__ h1g)
{
    __shared__ float xl[NN * 27];            // 10.8 KB
    __shared__ float dv[NN];
    __shared__ float Arow[NN];
    __shared__ float g1[27];
    const int tid = threadIdx.x, d = blockIdx.x;

    for (int i = tid; i < NN * 27; i += 256) xl[i] = x[i];
    if (tid < NN) {                          // dinv for all nodes
        float deg = 1.f;                     // self-loop weight
#pragma unroll 8
        for (int p = 0; p < NP; ++p) deg += D[p * NN + tid];
        dv[tid] = rsqrtf(deg);
    }
    __syncthreads();
    if (tid < NN) {                          // own Ssum row -> A row
        float s = 0.f;
#pragma unroll 8
        for (int p = 0; p < NP; ++p) s += P[p * 10000 + d * NN + tid];
        float v = dv[d] * dv[tid] * s;
        if (tid == d) v += dv[d] * dv[d];
        Arow[tid] = v;
        Ag[d * NN + tid] = v;
    }
    __syncthreads();
    if (tid < 27) {                          // g1 = A_row @ x
        float acc = 0.f;
#pragma unroll 4
        for (int m = 0; m < NN; ++m) acc += Arow[m] * xl[m * 27 + tid];
        g1[tid] = acc;
    }
    __syncthreads();
    if (tid < 64) {                          // h1 row = relu(g1 @ W1 + b1)
        float acc = b1[tid];
#pragma unroll
        for (int c = 0; c < 27; ++c) acc += g1[c] * W1[c * 64 + tid];
        h1g[d * 64 + tid] = fmaxf(acc, 0.f);
    }
}

// ---- 3. layer 2 (R6 verbatim) ----
__global__ __launch_bounds__(256) void l2_kernel(
    const float* __restrict__ A, const float* __restrict__ h1,
    const float* __restrict__ W2, const float* __restrict__ b2,
    float* __restrict__ h2)
{
    __shared__ float h1l[NN * 64];
    __shared__ float Ar[NN];
    __shared__ float g2[64];
    const int tid = threadIdx.x, n = blockIdx.x;
    for (int i = tid; i < NN * 16; i += 256)
        ((float4*)h1l)[i] = ((const float4*)h1)[i];
    if (tid < NN) Ar[tid] = A[n * NN + tid];
    __syncthreads();
    if (tid < 64) {
        float acc = 0.f;
#pragma unroll 4
        for (int m = 0; m < NN; ++m) acc += Ar[m] * h1l[m * 64 + tid];
        g2[tid] = acc;
    }
    __syncthreads();
    if (tid < 128) {
        float acc = b2[tid];
#pragma unroll 8
        for (int c = 0; c < 64; ++c) acc += g2[c] * W2[c * 128 + tid];
        h2[n * 128 + tid] = fmaxf(acc, 0.f);
    }
}

// ---- 4. layer 3 + BN stats (R6 verbatim) ----
__global__ __launch_bounds__(256) void l3_kernel(
    const float* __restrict__ A, const float* __restrict__ h2,
    const float* __restrict__ W3, const float* __restrict__ b3,
    float* __restrict__ h3, float* __restrict__ MS)
{
    __shared__ float h2l[NN * 128];
    __shared__ float Ar[NN];
    __shared__ float g3[128];
    const int tid = threadIdx.x, n = blockIdx.x;
    for (int i = tid; i < NN * 32; i += 256)
        ((float4*)h2l)[i] = ((const float4*)h2)[i];
    if (tid < NN) Ar[tid] = A[n * NN + tid];
    __syncthreads();
    if (tid < 128) {
        float acc = 0.f;
#pragma unroll 4
        for (int m = 0; m < NN; ++m) acc += Ar[m] * h2l[m * 128 + tid];
        g3[tid] = acc;
    }
    __syncthreads();
    {
        int j = tid;
        float acc = b3[j];
#pragma unroll 8
        for (int c = 0; c < 128; ++c) acc += g3[c] * W3[c * 256 + j];
        float v = fmaxf(acc, 0.f);
        h3[n * 256 + j] = v;
        atomicAdd(&MS[j], v);
        atomicAdd(&MS[256 + j], v * v);
    }
}

// ---- 5. tail: BN fold + redundant y + own out[j] (R8 verbatim) ----
__global__ __launch_bounds__(256) void tail_kernel(
    const float* __restrict__ h3g, const float* __restrict__ MS,
    const float* __restrict__ gamma, const float* __restrict__ beta,
    const float* __restrict__ lw1, const float* __restrict__ lb1,
    const float* __restrict__ lw2, const float* __restrict__ lb2,
    float* __restrict__ out)
{
    __shared__ float sc[256], sh[256];
    __shared__ float wsc[2560];              // sc-folded lw1
    __shared__ float cst[10];                // sh·lw1 + lb1
    __shared__ float yl[1000];
    __shared__ float partw[4];
    const int tid = threadIdx.x, j = blockIdx.x;

    {
        float s1 = MS[tid], s2 = MS[256 + tid];
        float mu  = s1 * 0.01f;
        float var = s2 * 0.01f - mu * mu;
        float s   = gamma[tid] * rsqrtf(var + 1e-5f);
        sc[tid] = s;
        sh[tid] = beta[tid] - mu * s;
    }
    __syncthreads();
    for (int i = tid; i < 2560; i += 256) wsc[i] = sc[i & 255] * lw1[i];
    if (tid < 10) {
        float a = lb1[tid];
        const float* w = lw1 + tid * 256;
#pragma unroll 4
        for (int c = 0; c < 256; ++c) a += sh[c] * w[c];
        cst[tid] = a;
    }
    __syncthreads();

    if (tid < 250) {                         // y redundant: 2n x 2k reg tiles
        int n0 = (tid / 5) * 2, k0 = (tid % 5) * 2;
        float a00 = 0.f, a01 = 0.f, a10 = 0.f, a11 = 0.f;
        for (int c = 0; c < 256; c += 4) {
            float4 hA = *(const float4*)(h3g + n0 * 256 + c);
            float4 hB = *(const float4*)(h3g + (n0 + 1) * 256 + c);
            float4 wA = *(const float4*)(wsc + k0 * 256 + c);
            float4 wB = *(const float4*)(wsc + (k0 + 1) * 256 + c);
            a00 += hA.x*wA.x + hA.y*wA.y + hA.z*wA.z + hA.w*wA.w;
            a01 += hA.x*wB.x + hA.y*wB.y + hA.z*wB.z + hA.w*wB.w;
            a10 += hB.x*wA.x + hB.y*wA.y + hB.z*wA.z + hB.w*wA.w;
            a11 += hB.x*wB.x + hB.y*wB.y + hB.z*wB.z + hB.w*wB.w;
        }
        yl[n0 * 10 + k0]           = fmaxf(a00 + cst[k0], 0.f);
        yl[n0 * 10 + k0 + 1]       = fmaxf(a01 + cst[k0 + 1], 0.f);
        yl[(n0 + 1) * 10 + k0]     = fmaxf(a10 + cst[k0], 0.f);
        yl[(n0 + 1) * 10 + k0 + 1] = fmaxf(a11 + cst[k0 + 1], 0.f);
    }
    __syncthreads();

    float acc = 0.f;
    if (tid < 250) {
        float4 a = ((const float4*)yl)[tid];
        float4 b = ((const float4*)(lw2 + j * 1000))[tid];
        acc = a.x * b.x + a.y * b.y + a.z * b.z + a.w * b.w;
    }
#pragma unroll
    for (int off = 32; off; off >>= 1) acc += __shfl_down(acc, off);
    if ((tid & 63) == 0) partw[tid >> 6] = acc;
    __syncthreads();
    if (tid == 0)
        out[j] = partw[0] + partw[1] + partw[2] + partw[3] + lb2[j];
}

extern "C" void kernel_launch(void* const* d_in, const int* in_sizes, int n_in,
                              void* d_out, int out_size, void* d_ws, size_t ws_size,
                              hipStream_t stream) {
    const float* x     = (const float*)d_in[0];
    const int*   ei    = (const int*)d_in[1];
    const float* ew    = (const float*)d_in[2];
    const float* W1    = (const float*)d_in[3];
    const float* b1    = (const float*)d_in[4];
    const float* W2    = (const float*)d_in[5];
    const float* b2    = (const float*)d_in[6];
    const float* W3    = (const float*)d_in[7];
    const float* b3    = (const float*)d_in[8];
    const float* gamma = (const float*)d_in[9];
    const float* beta  = (const float*)d_in[10];
    const float* lw1   = (const float*)d_in[11];
    const float* lb1   = (const float*)d_in[12];
    const float* lw2   = (const float*)d_in[13];
    const float* lb2   = (const float*)d_in[14];

    float* ws  = (float*)d_ws;
    float* P   = ws;
    float* D   = ws + WS_D;
    float* MS  = ws + WS_MS;
    float* A   = ws + WS_A;
    float* h1  = ws + WS_H1;
    float* h2  = ws + WS_H2;
    float* h3  = ws + WS_H3;
    float* out = (float*)d_out;

    scatter_kernel<<<NP, 512, 0, stream>>>(ei, ew, P, D, MS);
    a_l1_kernel<<<NN, 256, 0, stream>>>(P, D, x, W1, b1, A, h1);
    l2_kernel<<<NN, 256, 0, stream>>>(A, h1, W2, b2, h2);
    l3_kernel<<<NN, 256, 0, stream>>>(A, h2, W3, b3, h3, MS);
    tail_kernel<<<128, 256, 0, stream>>>(h3, MS, gamma, beta, lw1, lb1,
                                         lw2, lb2, out);
}